// Round 5
// baseline (85.092 us; speedup 1.0000x reference)
//
#include <hip/hip_runtime.h>
#include <hip/hip_bf16.h>
#include <stdint.h>
#include <stddef.h>

typedef __attribute__((ext_vector_type(8))) short short8;
typedef __attribute__((ext_vector_type(4))) float f32x4;
typedef __attribute__((ext_vector_type(4))) unsigned uint4v;

// Packed f32x2 -> bf16x2 (RTNE via scalar casts; compiler fuses).
__device__ inline unsigned pk2(float a, float b) {
    __hip_bfloat16 lo = __float2bfloat16(a);
    __hip_bfloat16 hi = __float2bfloat16(b);
    unsigned short ul = *reinterpret_cast<unsigned short*>(&lo);
    unsigned short uh = *reinterpret_cast<unsigned short*>(&hi);
    return (unsigned)ul | ((unsigned)uh << 16);
}

// ---------------- K1: node = mean(tf, axis=-1) ----------------
// 8192 blocks x 4 waves, 8 row-pairs per wave; 8 independent 1KB loads in
// flight per wave; interleaved shuffle chains.
__global__ __launch_bounds__(256) void k1_mean(const float* __restrict__ tf,
                                               float* __restrict__ node) {
    int wave = (blockIdx.x * blockDim.x + threadIdx.x) >> 6;  // 0..32767
    int lane = threadIdx.x & 63;
    int half = lane >> 5;
    int c = lane & 31;
    const float4* tf4 = reinterpret_cast<const float4*>(tf);
    size_t base = (size_t)wave * 8 * 64;

    float4 v[8];
#pragma unroll
    for (int k = 0; k < 8; ++k) v[k] = tf4[base + (size_t)k * 64 + lane];

    float s[8];
#pragma unroll
    for (int k = 0; k < 8; ++k) s[k] = (v[k].x + v[k].y) + (v[k].z + v[k].w);
#pragma unroll
    for (int m = 1; m <= 16; m <<= 1) {
#pragma unroll
        for (int k = 0; k < 8; ++k) s[k] += __shfl_xor(s[k], m);
    }
    if (c == 0) {
#pragma unroll
        for (int k = 0; k < 8; ++k) {
            int rp = wave * 8 + k;
            node[(size_t)rp * 2 + half] = s[k] * (1.0f / 128.0f);
        }
    }
}

// ---------------- K2: pi = node@Wi + b1, pj = node@Wj (MFMA) ----------------
__global__ __launch_bounds__(256) void k2_proj(const float* __restrict__ node,
                                               const float* __restrict__ W1,
                                               const float* __restrict__ b1,
                                               float* __restrict__ pi,
                                               float* __restrict__ pj) {
    const int LP = 136;
    __shared__ __align__(16) unsigned short A_lds[32 * LP];
    __shared__ __align__(16) unsigned short BT[128 * LP];
    __shared__ float b1s[128];

    int tid = threadIdx.x;
    int rblk = blockIdx.x >> 1;
    int half = blockIdx.x & 1;
    int r0 = rblk * 32;

    // Stage A: node rows -> bf16 LDS (row = tid>>3, 16 cols per thread)
    {
        int row = tid >> 3;
        int c0 = (tid & 7) * 16;
        const float4* src = reinterpret_cast<const float4*>(node + (size_t)(r0 + row) * 128 + c0);
        unsigned wb[8];
#pragma unroll
        for (int q = 0; q < 4; ++q) {
            float4 v = src[q];
            wb[2 * q + 0] = pk2(v.x, v.y);
            wb[2 * q + 1] = pk2(v.z, v.w);
        }
        uint4v* dst = reinterpret_cast<uint4v*>(&A_lds[row * LP + c0]);
        dst[0] = *reinterpret_cast<uint4v*>(&wb[0]);
        dst[1] = *reinterpret_cast<uint4v*>(&wb[4]);
    }
    // Stage BT[n][k] = W1[half*128+k][n]
    {
        int n = tid & 127;
        int kh = tid >> 7;
        const float* Wbase = W1 + (size_t)half * 128 * 128 + n;
#pragma unroll
        for (int g = 0; g < 8; ++g) {
            int kb = kh * 64 + g * 8;
            unsigned wb[4];
#pragma unroll
            for (int p = 0; p < 4; ++p)
                wb[p] = pk2(Wbase[(size_t)(kb + 2 * p) * 128], Wbase[(size_t)(kb + 2 * p + 1) * 128]);
            *reinterpret_cast<uint4v*>(&BT[n * LP + kb]) = *reinterpret_cast<uint4v*>(wb);
        }
    }
    if (tid < 128) b1s[tid] = b1[tid];
    __syncthreads();

    int w = tid >> 6;
    int l = tid & 63;
    int lr = l & 15;
    int lg = l >> 4;
    int rt = w & 1;
    int ch = w >> 1;

    f32x4 acc[4] = {{0,0,0,0},{0,0,0,0},{0,0,0,0},{0,0,0,0}};
#pragma unroll
    for (int ks = 0; ks < 4; ++ks) {
        int kb = ks * 32 + lg * 8;
        short8 afrag = *reinterpret_cast<const short8*>(&A_lds[(rt * 16 + lr) * LP + kb]);
#pragma unroll
        for (int nt = 0; nt < 4; ++nt) {
            short8 bfrag = *reinterpret_cast<const short8*>(&BT[(ch * 64 + nt * 16 + lr) * LP + kb]);
            acc[nt] = __builtin_amdgcn_mfma_f32_16x16x32_bf16(afrag, bfrag, acc[nt], 0, 0, 0);
        }
    }
    float* out = half ? pj : pi;
#pragma unroll
    for (int nt = 0; nt < 4; ++nt) {
        int col = ch * 64 + nt * 16 + lr;
        float bias = half ? 0.0f : b1s[col];
#pragma unroll
        for (int r = 0; r < 4; ++r) {
            int row = r0 + rt * 16 + lg * 4 + r;
            out[(size_t)row * 128 + col] = acc[nt][r] + bias;
        }
    }
}

// ---------------- K3: pairwise MLP via MFMA ----------------
// block = (b, i-tile of 4). 256 threads = 4 waves.
// W2T fragments hoisted to registers (iteration-invariant).
// pi row read directly from global (L2-hot) each iter; A built in LDS bf16.
__global__ __launch_bounds__(256) void k3_mlp(const float* __restrict__ pi,
                                              const float* __restrict__ pj,
                                              const float* __restrict__ W2,
                                              const float* __restrict__ b2,
                                              const float* __restrict__ W3,
                                              const float* __restrict__ b3,
                                              float* __restrict__ F) {
    const int LDA = 136;
    __shared__ __align__(16) unsigned short A_lds[64 * LDA];
    __shared__ __align__(16) unsigned short W2T[64 * LDA];
    __shared__ float b2s[64], w3s[64];

    int tid = threadIdx.x;
    int b = blockIdx.x >> 4;
    int it = blockIdx.x & 15;
    int i0 = it * 4;
    int jt = tid >> 2;  // 0..63
    int kq = tid & 3;   // k-chunk of 32

    // pj row chunk -> regs (reused for all 4 i's)
    float pjreg[32];
    {
        const float* src = pj + ((size_t)(b * 64 + jt) * 128 + kq * 32);
#pragma unroll
        for (int e = 0; e < 8; ++e) {
            float4 v = reinterpret_cast<const float4*>(src)[e];
            pjreg[e * 4 + 0] = v.x;
            pjreg[e * 4 + 1] = v.y;
            pjreg[e * 4 + 2] = v.z;
            pjreg[e * 4 + 3] = v.w;
        }
    }
    // W2T[m][k] = W2[k][m], packed b128 writes
    {
        int m = jt;
#pragma unroll
        for (int g = 0; g < 4; ++g) {
            unsigned wb[4];
#pragma unroll
            for (int p = 0; p < 4; ++p) {
                int k = kq * 32 + g * 8 + p * 2;
                wb[p] = pk2(W2[(size_t)k * 64 + m], W2[(size_t)(k + 1) * 64 + m]);
            }
            *reinterpret_cast<uint4v*>(&W2T[m * LDA + kq * 32 + g * 8]) = *reinterpret_cast<uint4v*>(wb);
        }
    }
    if (tid < 64) {
        b2s[tid] = b2[tid];
        w3s[tid] = W3[tid];
    }
    float b3v = b3[0];
    __syncthreads();

    int w = tid >> 6;
    int l = tid & 63;
    int lr = l & 15;
    int lg = l >> 4;

    // Hoist W2T fragments (iteration-invariant): 16 x short8 = 64 VGPR
    short8 bfr[4][4];
#pragma unroll
    for (int ks = 0; ks < 4; ++ks) {
        int kb = ks * 32 + lg * 8;
#pragma unroll
        for (int nt = 0; nt < 4; ++nt)
            bfr[ks][nt] = *reinterpret_cast<const short8*>(&W2T[(nt * 16 + lr) * LDA + kb]);
    }

    for (int il = 0; il < 4; ++il) {
        int i = i0 + il;
        __syncthreads();  // prev-iter A_lds reads done
        // Build A tile: A[j][k] = relu(pi[b,i,k] + pj[b,j,k]), bf16 packed
        {
            const float4* pisrc = reinterpret_cast<const float4*>(pi + ((size_t)(b * 64 + i) * 128 + kq * 32));
            unsigned wbuf[16];
#pragma unroll
            for (int e = 0; e < 8; ++e) {
                float4 v = pisrc[e];
                float a0 = fmaxf(v.x + pjreg[4 * e + 0], 0.0f);
                float a1 = fmaxf(v.y + pjreg[4 * e + 1], 0.0f);
                float a2 = fmaxf(v.z + pjreg[4 * e + 2], 0.0f);
                float a3 = fmaxf(v.w + pjreg[4 * e + 3], 0.0f);
                wbuf[2 * e + 0] = pk2(a0, a1);
                wbuf[2 * e + 1] = pk2(a2, a3);
            }
            uint4v* dst = reinterpret_cast<uint4v*>(&A_lds[jt * LDA + kq * 32]);
#pragma unroll
            for (int q = 0; q < 4; ++q) dst[q] = *reinterpret_cast<uint4v*>(&wbuf[4 * q]);
        }
        __syncthreads();
        // MFMA: M=16 (j-tile), N=64 (4 m-tiles), K=128 (4 k-slices)
        f32x4 acc[4] = {{0,0,0,0},{0,0,0,0},{0,0,0,0},{0,0,0,0}};
#pragma unroll
        for (int ks = 0; ks < 4; ++ks) {
            int kb = ks * 32 + lg * 8;
            short8 afrag = *reinterpret_cast<const short8*>(&A_lds[(w * 16 + lr) * LDA + kb]);
#pragma unroll
            for (int nt = 0; nt < 4; ++nt)
                acc[nt] = __builtin_amdgcn_mfma_f32_16x16x32_bf16(afrag, bfr[ks][nt], acc[nt], 0, 0, 0);
        }
        // feat = sum_m relu(C + b2[m]) * W3[m]; C: col(m)=lane&15, row(j)=(lane>>4)*4+r
        float part[4] = {0.f, 0.f, 0.f, 0.f};
#pragma unroll
        for (int mt = 0; mt < 4; ++mt) {
            int m = mt * 16 + lr;
            float w3 = w3s[m];
            float bb = b2s[m];
#pragma unroll
            for (int r = 0; r < 4; ++r) {
                float h = fmaxf(acc[mt][r] + bb, 0.0f);
                part[r] += h * w3;
            }
        }
#pragma unroll
        for (int r = 0; r < 4; ++r) {
            part[r] += __shfl_xor(part[r], 1);
            part[r] += __shfl_xor(part[r], 2);
            part[r] += __shfl_xor(part[r], 4);
            part[r] += __shfl_xor(part[r], 8);
        }
        if (lr == 0) {
#pragma unroll
            for (int r = 0; r < 4; ++r) {
                int j = w * 16 + lg * 4 + r;
                F[((size_t)b * 64 + i) * 64 + j] = part[r] + b3v;
            }
        }
    }
}

// ---------------- K4: symmetrize + eye + row-normalize ----------------
__global__ __launch_bounds__(256) void k4_final(const float* __restrict__ F,
                                                const float* __restrict__ ap,
                                                float* __restrict__ out) {
    __shared__ float s[64][65];
    __shared__ float rs[64];
    int b = blockIdx.x;
    int tid = threadIdx.x;
    for (int idx = tid; idx < 4096; idx += 256) {
        int i = idx >> 6, j = idx & 63;
        float f_ij = F[(size_t)b * 4096 + idx];
        float f_ji = F[(size_t)b * 4096 + j * 64 + i];
        float a_ij = ap[idx];
        float a_ji = ap[j * 64 + i];
        float v = 0.25f * (a_ij + a_ji) + 0.25f * (f_ij + f_ji);
        v = fmaxf(v, 0.0f);
        if (i == j) v += 1.0f;
        s[i][j] = v;
    }
    __syncthreads();
    int wv = tid >> 6, ln = tid & 63;
    for (int i = wv * 16; i < wv * 16 + 16; ++i) {
        float v = s[i][ln];
        v += __shfl_xor(v, 1);
        v += __shfl_xor(v, 2);
        v += __shfl_xor(v, 4);
        v += __shfl_xor(v, 8);
        v += __shfl_xor(v, 16);
        v += __shfl_xor(v, 32);
        if (ln == 0) rs[i] = v;
    }
    __syncthreads();
    for (int idx = tid; idx < 4096; idx += 256) {
        int i = idx >> 6, j = idx & 63;
        out[(size_t)b * 4096 + idx] = s[i][j] / (rs[i] + 1e-8f);
    }
}

extern "C" void kernel_launch(void* const* d_in, const int* in_sizes, int n_in,
                              void* d_out, int out_size, void* d_ws, size_t ws_size,
                              hipStream_t stream) {
    const float* tf = (const float*)d_in[0];
    const float* ap = (const float*)d_in[1];
    const float* W1 = (const float*)d_in[2];
    const float* b1 = (const float*)d_in[3];
    const float* W2 = (const float*)d_in[4];
    const float* b2 = (const float*)d_in[5];
    const float* W3 = (const float*)d_in[6];
    const float* b3 = (const float*)d_in[7];
    float* out = (float*)d_out;

    char* ws = (char*)d_ws;
    float* node = (float*)(ws);                          // 2 MB
    float* pi   = (float*)(ws + (size_t)(2 << 20));      // 2 MB (pi + b1)
    float* pj   = (float*)(ws + (size_t)(4 << 20));      // 2 MB
    float* F    = (float*)(ws + (size_t)(6 << 20));      // 1 MB

    k1_mean<<<8192, 256, 0, stream>>>(tf, node);
    k2_proj<<<256, 256, 0, stream>>>(node, W1, b1, pi, pj);
    k3_mlp<<<1024, 256, 0, stream>>>(pi, pj, W2, b2, W3, b3, F);
    k4_final<<<64, 256, 0, stream>>>(F, ap, out);
}

// Round 6
// 77.074 us; speedup vs baseline: 1.1040x; 1.1040x over previous
//
#include <hip/hip_runtime.h>
#include <stdint.h>
#include <stddef.h>

typedef __attribute__((ext_vector_type(8))) short short8;
typedef __attribute__((ext_vector_type(4))) float f32x4;

__device__ inline unsigned short f2bf(float x) {
    unsigned u = __float_as_uint(x);
    unsigned r = (u + 0x7fffu + ((u >> 16) & 1u)) >> 16;
    return (unsigned short)r;
}

// ---------------- K1: node = mean(tf, axis=-1) ----------------
// 8192 blocks x 4 waves, 8 row-pairs per wave; 8 independent 1KB loads in
// flight per wave; interleaved shuffle chains.
__global__ __launch_bounds__(256) void k1_mean(const float* __restrict__ tf,
                                               float* __restrict__ node) {
    int wave = (blockIdx.x * blockDim.x + threadIdx.x) >> 6;  // 0..32767
    int lane = threadIdx.x & 63;
    int half = lane >> 5;
    int c = lane & 31;
    const float4* tf4 = reinterpret_cast<const float4*>(tf);
    size_t base = (size_t)wave * 8 * 64;

    float4 v[8];
#pragma unroll
    for (int k = 0; k < 8; ++k) v[k] = tf4[base + (size_t)k * 64 + lane];

    float s[8];
#pragma unroll
    for (int k = 0; k < 8; ++k) s[k] = (v[k].x + v[k].y) + (v[k].z + v[k].w);
#pragma unroll
    for (int m = 1; m <= 16; m <<= 1) {
#pragma unroll
        for (int k = 0; k < 8; ++k) s[k] += __shfl_xor(s[k], m);
    }
    if (c == 0) {
#pragma unroll
        for (int k = 0; k < 8; ++k) {
            int rp = wave * 8 + k;
            node[(size_t)rp * 2 + half] = s[k] * (1.0f / 128.0f);
        }
    }
}

// ---------------- K2: pi = node@Wi + b1, pj = node@Wj (MFMA) ----------------
__global__ __launch_bounds__(256) void k2_proj(const float* __restrict__ node,
                                               const float* __restrict__ W1,
                                               const float* __restrict__ b1,
                                               float* __restrict__ pi,
                                               float* __restrict__ pj) {
    const int LP = 136;
    __shared__ unsigned short A_lds[32 * LP];
    __shared__ unsigned short BT[128 * LP];
    __shared__ float b1s[128];

    int tid = threadIdx.x;
    int rblk = blockIdx.x >> 1;
    int half = blockIdx.x & 1;
    int r0 = rblk * 32;

    // Stage A: node rows -> bf16 LDS (row = tid>>3, 16 cols per thread)
    {
        int row = tid >> 3;
        int c0 = (tid & 7) * 16;
        const float4* src = reinterpret_cast<const float4*>(node + (size_t)(r0 + row) * 128 + c0);
        short8 pk[2];
#pragma unroll
        for (int q = 0; q < 2; ++q) {
            float4 va = src[q * 2 + 0];
            float4 vb = src[q * 2 + 1];
            pk[q][0] = (short)f2bf(va.x); pk[q][1] = (short)f2bf(va.y);
            pk[q][2] = (short)f2bf(va.z); pk[q][3] = (short)f2bf(va.w);
            pk[q][4] = (short)f2bf(vb.x); pk[q][5] = (short)f2bf(vb.y);
            pk[q][6] = (short)f2bf(vb.z); pk[q][7] = (short)f2bf(vb.w);
        }
        short8* dst = reinterpret_cast<short8*>(&A_lds[row * LP + c0]);
        dst[0] = pk[0];
        dst[1] = pk[1];
    }
    // Stage BT: thread t: n = t&127, k-half kh = t>>7 (64 k's), packed b128 writes.
    {
        int n = tid & 127;
        int kh = tid >> 7;
        const float* Wbase = W1 + (size_t)half * 128 * 128 + n;
#pragma unroll
        for (int g = 0; g < 8; ++g) {
            int kb = kh * 64 + g * 8;
            short8 pk;
#pragma unroll
            for (int e = 0; e < 8; ++e) pk[e] = (short)f2bf(Wbase[(size_t)(kb + e) * 128]);
            *reinterpret_cast<short8*>(&BT[n * LP + kb]) = pk;
        }
    }
    if (tid < 128) b1s[tid] = b1[tid];
    __syncthreads();

    int w = tid >> 6;
    int l = tid & 63;
    int lr = l & 15;
    int lg = l >> 4;
    int rt = w & 1;
    int ch = w >> 1;

    f32x4 acc[4] = {{0,0,0,0},{0,0,0,0},{0,0,0,0},{0,0,0,0}};
#pragma unroll
    for (int ks = 0; ks < 4; ++ks) {
        int kb = ks * 32 + lg * 8;
        short8 afrag = *reinterpret_cast<const short8*>(&A_lds[(rt * 16 + lr) * LP + kb]);
#pragma unroll
        for (int nt = 0; nt < 4; ++nt) {
            short8 bfrag = *reinterpret_cast<const short8*>(&BT[(ch * 64 + nt * 16 + lr) * LP + kb]);
            acc[nt] = __builtin_amdgcn_mfma_f32_16x16x32_bf16(afrag, bfrag, acc[nt], 0, 0, 0);
        }
    }
    float* out = half ? pj : pi;
#pragma unroll
    for (int nt = 0; nt < 4; ++nt) {
        int col = ch * 64 + nt * 16 + lr;
        float bias = half ? 0.0f : b1s[col];
#pragma unroll
        for (int r = 0; r < 4; ++r) {
            int row = r0 + rt * 16 + lg * 4 + r;
            out[(size_t)row * 128 + col] = acc[nt][r] + bias;
        }
    }
}

// ---------------- K3: pairwise MLP via MFMA ----------------
// block = (b, i-tile of 4). 256 threads = 4 waves.
// ALL 4 pi rows prefetched to LDS at block start -> loop body is LDS-only:
// {A-build; barrier; MFMA+epilogue; barrier} x4 (no global latency inside).
__global__ __launch_bounds__(256) void k3_mlp(const float* __restrict__ pi,
                                              const float* __restrict__ pj,
                                              const float* __restrict__ W2,
                                              const float* __restrict__ b2,
                                              const float* __restrict__ W3,
                                              const float* __restrict__ b3,
                                              float* __restrict__ F) {
    const int LDA = 136;  // bf16 elements per row (padded from 128)
    __shared__ unsigned short A_lds[64 * LDA];
    __shared__ unsigned short W2T[64 * LDA];
    __shared__ float pipb4[4][128];
    __shared__ float b2s[64], w3s[64];

    int tid = threadIdx.x;
    int b = blockIdx.x >> 4;
    int it = blockIdx.x & 15;
    int i0 = it * 4;
    int jt = tid >> 2;  // 0..63
    int kq = tid & 3;   // k-chunk of 32

    // pj row chunk -> regs (reused for all 4 i's)
    float pjreg[32];
    {
        const float* src = pj + ((size_t)(b * 64 + jt) * 128 + kq * 32);
#pragma unroll
        for (int e = 0; e < 8; ++e) {
            float4 v = reinterpret_cast<const float4*>(src)[e];
            pjreg[e * 4 + 0] = v.x;
            pjreg[e * 4 + 1] = v.y;
            pjreg[e * 4 + 2] = v.z;
            pjreg[e * 4 + 3] = v.w;
        }
    }
    // Prefetch pi rows i0..i0+3 (already includes b1): 128 threads x float4
    if (tid < 128) {
        int row = tid >> 5;
        int c4 = tid & 31;
        float4 v = reinterpret_cast<const float4*>(pi + ((size_t)(b * 64 + i0 + row) * 128))[c4];
        reinterpret_cast<float4*>(&pipb4[row][0])[c4] = v;
    }
    // W2T build: W2 is (128,64) row-major; W2T[m][k] = W2[k][m]
    {
        int m = jt;
        for (int e = 0; e < 32; ++e) {
            int k = kq * 32 + e;
            W2T[m * LDA + k] = f2bf(W2[(size_t)k * 64 + m]);
        }
    }
    if (tid < 64) {
        b2s[tid] = b2[tid];
        w3s[tid] = W3[tid];
    }
    float b3v = b3[0];
    __syncthreads();  // all staging (pipb4, W2T, b2s/w3s) done

    int w = tid >> 6;   // wave id
    int l = tid & 63;
    int lr = l & 15;
    int lg = l >> 4;

    for (int il = 0; il < 4; ++il) {
        // Build A tile (bf16, padded): A[j][k] = relu(pi[i0+il,k] + pj[j,k])
        {
            unsigned* dst = reinterpret_cast<unsigned*>(&A_lds[jt * LDA + kq * 32]);
#pragma unroll
            for (int e2 = 0; e2 < 16; ++e2) {
                float a0 = pipb4[il][kq * 32 + e2 * 2 + 0] + pjreg[e2 * 2 + 0];
                float a1 = pipb4[il][kq * 32 + e2 * 2 + 1] + pjreg[e2 * 2 + 1];
                a0 = fmaxf(a0, 0.0f);
                a1 = fmaxf(a1, 0.0f);
                dst[e2] = (unsigned)f2bf(a0) | ((unsigned)f2bf(a1) << 16);
            }
        }
        __syncthreads();  // A ready
        // MFMA: M=16 (j-tile), N=64 (4 m-tiles), K=128 (4 k-slices)
        f32x4 acc0 = {0.f, 0.f, 0.f, 0.f};
        f32x4 acc1 = {0.f, 0.f, 0.f, 0.f};
        f32x4 acc2 = {0.f, 0.f, 0.f, 0.f};
        f32x4 acc3 = {0.f, 0.f, 0.f, 0.f};
#pragma unroll
        for (int ks = 0; ks < 4; ++ks) {
            int kb = ks * 32 + lg * 8;
            short8 afrag = *reinterpret_cast<const short8*>(&A_lds[(w * 16 + lr) * LDA + kb]);
            short8 b0 = *reinterpret_cast<const short8*>(&W2T[(0 * 16 + lr) * LDA + kb]);
            short8 b1f = *reinterpret_cast<const short8*>(&W2T[(1 * 16 + lr) * LDA + kb]);
            short8 b2f = *reinterpret_cast<const short8*>(&W2T[(2 * 16 + lr) * LDA + kb]);
            short8 b3f = *reinterpret_cast<const short8*>(&W2T[(3 * 16 + lr) * LDA + kb]);
            acc0 = __builtin_amdgcn_mfma_f32_16x16x32_bf16(afrag, b0, acc0, 0, 0, 0);
            acc1 = __builtin_amdgcn_mfma_f32_16x16x32_bf16(afrag, b1f, acc1, 0, 0, 0);
            acc2 = __builtin_amdgcn_mfma_f32_16x16x32_bf16(afrag, b2f, acc2, 0, 0, 0);
            acc3 = __builtin_amdgcn_mfma_f32_16x16x32_bf16(afrag, b3f, acc3, 0, 0, 0);
        }
        // feat = sum_m relu(C + b2[m]) * W3[m]  (C: col=lane&15, row=(lane>>4)*4+r)
        float part[4] = {0.f, 0.f, 0.f, 0.f};
#pragma unroll
        for (int mt = 0; mt < 4; ++mt) {
            int m = mt * 16 + lr;
            float w3 = w3s[m];
            float bb = b2s[m];
            f32x4 a = (mt == 0) ? acc0 : (mt == 1) ? acc1 : (mt == 2) ? acc2 : acc3;
#pragma unroll
            for (int r = 0; r < 4; ++r) {
                float h = fmaxf(a[r] + bb, 0.0f);
                part[r] += h * w3;
            }
        }
#pragma unroll
        for (int r = 0; r < 4; ++r) {
            part[r] += __shfl_xor(part[r], 1);
            part[r] += __shfl_xor(part[r], 2);
            part[r] += __shfl_xor(part[r], 4);
            part[r] += __shfl_xor(part[r], 8);
        }
        if (lr == 0) {
#pragma unroll
            for (int r = 0; r < 4; ++r) {
                int j = w * 16 + lg * 4 + r;
                F[((size_t)b * 64 + i0 + il) * 64 + j] = part[r] + b3v;
            }
        }
        __syncthreads();  // A_lds consumed; safe to overwrite next iter
    }
}

// ---------------- K4: symmetrize + eye + row-normalize ----------------
__global__ __launch_bounds__(256) void k4_final(const float* __restrict__ F,
                                                const float* __restrict__ ap,
                                                float* __restrict__ out) {
    __shared__ float s[64][65];
    __shared__ float rs[64];
    int b = blockIdx.x;
    int tid = threadIdx.x;
    for (int idx = tid; idx < 4096; idx += 256) {
        int i = idx >> 6, j = idx & 63;
        float f_ij = F[(size_t)b * 4096 + idx];
        float f_ji = F[(size_t)b * 4096 + j * 64 + i];
        float a_ij = ap[idx];
        float a_ji = ap[j * 64 + i];
        float v = 0.25f * (a_ij + a_ji) + 0.25f * (f_ij + f_ji);
        v = fmaxf(v, 0.0f);
        if (i == j) v += 1.0f;
        s[i][j] = v;
    }
    __syncthreads();
    int wv = tid >> 6, ln = tid & 63;
    for (int i = wv * 16; i < wv * 16 + 16; ++i) {
        float v = s[i][ln];
        v += __shfl_xor(v, 1);
        v += __shfl_xor(v, 2);
        v += __shfl_xor(v, 4);
        v += __shfl_xor(v, 8);
        v += __shfl_xor(v, 16);
        v += __shfl_xor(v, 32);
        if (ln == 0) rs[i] = v;
    }
    __syncthreads();
    for (int idx = tid; idx < 4096; idx += 256) {
        int i = idx >> 6, j = idx & 63;
        out[(size_t)b * 4096 + idx] = s[i][j] / (rs[i] + 1e-8f);
    }
}

extern "C" void kernel_launch(void* const* d_in, const int* in_sizes, int n_in,
                              void* d_out, int out_size, void* d_ws, size_t ws_size,
                              hipStream_t stream) {
    const float* tf = (const float*)d_in[0];
    const float* ap = (const float*)d_in[1];
    const float* W1 = (const float*)d_in[2];
    const float* b1 = (const float*)d_in[3];
    const float* W2 = (const float*)d_in[4];
    const float* b2 = (const float*)d_in[5];
    const float* W3 = (const float*)d_in[6];
    const float* b3 = (const float*)d_in[7];
    float* out = (float*)d_out;

    char* ws = (char*)d_ws;
    float* node = (float*)(ws);                          // 2 MB
    float* pi   = (float*)(ws + (size_t)(2 << 20));      // 2 MB (pi + b1)
    float* pj   = (float*)(ws + (size_t)(4 << 20));      // 2 MB
    float* F    = (float*)(ws + (size_t)(6 << 20));      // 1 MB

    k1_mean<<<8192, 256, 0, stream>>>(tf, node);
    k2_proj<<<256, 256, 0, stream>>>(node, W1, b1, pi, pj);
    k3_mlp<<<1024, 256, 0, stream>>>(pi, pj, W2, b2, W3, b3, F);
    k4_final<<<64, 256, 0, stream>>>(F, ap, out);
}